// Round 1
// baseline (321.551 us; speedup 1.0000x reference)
//
#include <hip/hip_runtime.h>

#define H 1024
#define E 8
#define TT 64          // tokens per block
#define HC 64          // H-chunk per LDS tile
#define HSTRIDE 68     // padded LDS row stride (16B-aligned, bank-clean)
#define NCHUNK (H / HC)
#define BLK 256
#define CAP 5120       // int(1.25 * 4096 * 8 / 8)
#define CBLK 1024

// ---------------------------------------------------------------------------
// Kernel 1: router logits (GEMM N x 1024 x 8), softmax, top-2 renorm,
// write router_probs + dispatch_mask, accumulate per-expert sums.
// ---------------------------------------------------------------------------
__global__ __launch_bounds__(BLK) void router_kernel(
    const float* __restrict__ hs,
    const float* __restrict__ rw,
    float* __restrict__ dispatch,
    float* __restrict__ probs_out,
    float* __restrict__ gsums)   // [0..7] tokens_per_expert, [8..15] prob sums
{
    __shared__ float w_lds[E * H];           // 32 KB
    __shared__ float h_lds[TT * HSTRIDE];    // 17.4 KB (also reused as `red`)

    const int tid = threadIdx.x;

    // Stage router_w into LDS (coalesced float4)
    for (int i = tid; i < E * H / 4; i += BLK)
        ((float4*)w_lds)[i] = ((const float4*)rw)[i];

    const int t0   = blockIdx.x * TT;
    const int lane = tid & 63;   // token within tile (compute phase)
    const int part = tid >> 6;   // H-quarter (wave-uniform)

    float acc[E];
#pragma unroll
    for (int e = 0; e < E; ++e) acc[e] = 0.f;

    const int f4   = tid & 15;   // float4 slot within a 64-float row
    const int trow = tid >> 4;   // 0..15

    for (int c = 0; c < NCHUNK; ++c) {
        __syncthreads();  // protect h_lds reuse (also fences w_lds on c==0)
        // Load 64 tokens x 64 floats, coalesced in 256B runs
#pragma unroll
        for (int r = 0; r < 4; ++r) {
            const int t = trow + r * 16;
            const float4 v = *(const float4*)(hs + (size_t)(t0 + t) * H + c * HC + f4 * 4);
            *(float4*)(h_lds + t * HSTRIDE + f4 * 4) = v;
        }
        __syncthreads();
        const float* hrow  = h_lds + lane * HSTRIDE + part * 16;
        const float* wbase = w_lds + c * HC + part * 16;
#pragma unroll
        for (int k4 = 0; k4 < 4; ++k4) {
            const float4 hv = *(const float4*)(hrow + k4 * 4);
#pragma unroll
            for (int e = 0; e < E; ++e) {
                const float4 wv = *(const float4*)(wbase + e * H + k4 * 4);
                acc[e] = fmaf(hv.x, wv.x, acc[e]);
                acc[e] = fmaf(hv.y, wv.y, acc[e]);
                acc[e] = fmaf(hv.z, wv.z, acc[e]);
                acc[e] = fmaf(hv.w, wv.w, acc[e]);
            }
        }
    }

    // Combine the 4 H-quarters per token via LDS (reuse h_lds)
    __syncthreads();
    float* red = h_lds;
    if (part != 0) {
#pragma unroll
        for (int e = 0; e < E; ++e)
            red[((part - 1) * TT + lane) * E + e] = acc[e];
    }
    __syncthreads();

    if (part == 0) {
#pragma unroll
        for (int e = 0; e < E; ++e)
            acc[e] += red[(0 * TT + lane) * E + e]
                    + red[(1 * TT + lane) * E + e]
                    + red[(2 * TT + lane) * E + e];

        // softmax over E=8 (TEMPERATURE = 1)
        float mx = acc[0];
#pragma unroll
        for (int e = 1; e < E; ++e) mx = fmaxf(mx, acc[e]);
        float p[E];
        float s = 0.f;
#pragma unroll
        for (int e = 0; e < E; ++e) { p[e] = expf(acc[e] - mx); s += p[e]; }
        const float inv = 1.f / s;
#pragma unroll
        for (int e = 0; e < E; ++e) p[e] *= inv;

        // top-2 (strict >, keeps lowest index on ties — matches lax.top_k)
        int i1 = 0;
#pragma unroll
        for (int e = 1; e < E; ++e) if (p[e] > p[i1]) i1 = e;
        int i2 = -1;
#pragma unroll
        for (int e = 0; e < E; ++e) {
            if (e == i1) continue;
            if (i2 < 0 || p[e] > p[i2]) i2 = e;
        }
        const float s12 = p[i1] + p[i2];
        const float w1 = p[i1] / s12;
        const float w2 = p[i2] / s12;

        const size_t token = (size_t)t0 + lane;
#pragma unroll
        for (int e = 0; e < E; ++e) {
            const float de = (e == i1) ? w1 : ((e == i2) ? w2 : 0.f);
            dispatch[token * E + e]  = de;
            probs_out[token * E + e] = p[e];
            // wave-level reduction across the 64 tokens of this block
            float v1 = de, v2 = p[e];
#pragma unroll
            for (int off = 32; off > 0; off >>= 1) {
                v1 += __shfl_xor(v1, off);
                v2 += __shfl_xor(v2, off);
            }
            if (lane == 0) {
                atomicAdd(&gsums[e], v1);
                atomicAdd(&gsums[E + e], v2);
            }
        }
    }
}

// ---------------------------------------------------------------------------
// Kernel 2: lb_loss scalar + per-expert capacity enforcement (exact radix
// select over float bits, index-ordered tie-break = lax.top_k semantics).
// One block per expert; early-exits unless tokens_per_expert > capacity.
// ---------------------------------------------------------------------------
__global__ __launch_bounds__(CBLK) void capacity_kernel(
    float* __restrict__ dispatch,
    const float* __restrict__ gsums,
    float* __restrict__ lb_out,
    int N)
{
    const int e   = blockIdx.x;
    const int tid = threadIdx.x;

    if (e == 0 && tid == 0) {
        float s = 0.f;
        for (int i = 0; i < E; ++i) s += gsums[i] * gsums[E + i];
        *lb_out = 0.01f * s / (float)N;
    }

    if (!(gsums[e] > (float)CAP)) return;   // wave-uniform per block

    __shared__ unsigned hist[256];
    __shared__ unsigned sh_prefix;
    __shared__ int sh_k;

    unsigned prefix = 0;
    int k = CAP;

    // 4 x 8-bit radix rounds: find exact bit pattern T of the k-th largest
    for (int round = 0; round < 4; ++round) {
        const int shift = 24 - 8 * round;
        for (int i = tid; i < 256; i += CBLK) hist[i] = 0;
        __syncthreads();
        const unsigned mhi = (round == 0) ? 0u : (0xFFFFFFFFu << (shift + 8));
        for (int i = tid; i < N; i += CBLK) {
            const unsigned bits = __float_as_uint(dispatch[(size_t)i * E + e]);
            if ((bits & mhi) == (prefix & mhi))
                atomicAdd(&hist[(bits >> shift) & 255u], 1u);
        }
        __syncthreads();
        if (tid == 0) {
            int cum = 0;
            int d = 255;
            for (; d > 0; --d) {
                const int h = (int)hist[d];
                if (cum + h >= k) break;
                cum += h;
            }
            sh_prefix = prefix | ((unsigned)d << shift);
            sh_k = k - cum;
        }
        __syncthreads();
        prefix = sh_prefix;
        k = sh_k;
        __syncthreads();
    }

    const unsigned T = prefix;
    const unsigned r = (unsigned)k;   // keep first r values == T, by token index

    __shared__ unsigned wave_cnt[CBLK / 64];
    __shared__ unsigned running;
    if (tid == 0) running = 0;
    __syncthreads();

    const int lane = tid & 63;
    const int wv   = tid >> 6;
    const int nw   = CBLK / 64;

    for (int base = 0; base < N; base += CBLK) {
        const int i = base + tid;
        const unsigned bits = __float_as_uint(dispatch[(size_t)i * E + e]);
        const bool eq = (bits == T);
        const unsigned long long bal = __ballot(eq);
        if (lane == 0) wave_cnt[wv] = (unsigned)__popcll(bal);
        __syncthreads();
        unsigned before = running;
        for (int w = 0; w < wv; ++w) before += wave_cnt[w];
        const unsigned rank = before + (unsigned)__popcll(bal & ((1ull << lane) - 1ull));
        const bool keep = (bits > T) || (eq && rank < r);
        if (!keep) dispatch[(size_t)i * E + e] = 0.f;
        __syncthreads();
        if (tid == 0) {
            unsigned tot = 0;
            for (int w = 0; w < nw; ++w) tot += wave_cnt[w];
            running += tot;
        }
        __syncthreads();
    }
}

// ---------------------------------------------------------------------------
extern "C" void kernel_launch(void* const* d_in, const int* in_sizes, int n_in,
                              void* d_out, int out_size, void* d_ws, size_t ws_size,
                              hipStream_t stream)
{
    const float* hs = (const float*)d_in[0];
    const float* rw = (const float*)d_in[1];
    const int n_tokens = in_sizes[0] / H;   // 32768

    float* dispatch = (float*)d_out;                      // [N*E]
    float* lb       = dispatch + (size_t)n_tokens * E;    // [1]
    float* probs    = lb + 1;                             // [N*E]
    float* gsums    = (float*)d_ws;                       // [16] fp32

    hipMemsetAsync(gsums, 0, 2 * E * sizeof(float), stream);
    router_kernel<<<n_tokens / TT, BLK, 0, stream>>>(hs, rw, dispatch, probs, gsums);
    capacity_kernel<<<E, CBLK, 0, stream>>>(dispatch, gsums, lb, n_tokens);
}

// Round 2
// 216.390 us; speedup vs baseline: 1.4860x; 1.4860x over previous
//
#include <hip/hip_runtime.h>

#define H 1024
#define E 8
#define BLK 256
#define CAP 5120       // int(1.25 * 4096 * 8 / 8)
#define FBLK 1024

// ---------------------------------------------------------------------------
// Kernel 1: router logits + softmax + top-2 renorm + outputs + per-block
// partial sums (tokens_per_expert, prob sums).
// Wave layout: lane = (t<<4)|f ; t = token-slot (4), f = H-slice (16).
// Each lane handles 2 tokens (tok0, tok0+1): 8 tokens per wave.
// ---------------------------------------------------------------------------
__global__ __launch_bounds__(BLK) void router_kernel(
    const float* __restrict__ hs,
    const float* __restrict__ rw,
    float* __restrict__ dispatch,
    float* __restrict__ probs_out,
    float* __restrict__ partial)   // [gridDim.x][16]
{
    __shared__ float w_lds[E * H];   // 32 KB, read-only after first barrier

    const int tid = threadIdx.x;
    for (int i = tid; i < E * H / 4; i += BLK)
        ((float4*)w_lds)[i] = ((const float4*)rw)[i];
    __syncthreads();

    const int wave = tid >> 6;
    const int lane = tid & 63;
    const int t    = lane >> 4;     // token slot within wave
    const int f    = lane & 15;     // H-slice: covers H indices c*64 + 4f..+3
    const int wid  = blockIdx.x * (BLK / 64) + wave;
    const size_t tok0 = (size_t)wid * 8 + t * 2;

    float acc0[E], acc1[E];
#pragma unroll
    for (int e = 0; e < E; ++e) { acc0[e] = 0.f; acc1[e] = 0.f; }

    const float* h0 = hs + tok0 * H + 4 * f;

#pragma unroll 4
    for (int c = 0; c < 16; ++c) {
        const float4 a0 = *(const float4*)(h0 + c * 64);          // coalesced 256B runs
        const float4 a1 = *(const float4*)(h0 + H + c * 64);
        const float* wb = w_lds + c * 64 + 4 * f;
#pragma unroll
        for (int e = 0; e < E; ++e) {
            const float4 wv = *(const float4*)(wb + e * H);       // 2-way alias = free
            acc0[e] = fmaf(a0.x, wv.x, acc0[e]);
            acc0[e] = fmaf(a0.y, wv.y, acc0[e]);
            acc0[e] = fmaf(a0.z, wv.z, acc0[e]);
            acc0[e] = fmaf(a0.w, wv.w, acc0[e]);
            acc1[e] = fmaf(a1.x, wv.x, acc1[e]);
            acc1[e] = fmaf(a1.y, wv.y, acc1[e]);
            acc1[e] = fmaf(a1.z, wv.z, acc1[e]);
            acc1[e] = fmaf(a1.w, wv.w, acc1[e]);
        }
    }

    // Reduce partial dots across the 16 f-lanes (butterfly: all lanes get sum)
#pragma unroll
    for (int e = 0; e < E; ++e) {
        float v0 = acc0[e], v1 = acc1[e];
        v0 += __shfl_xor(v0, 1); v1 += __shfl_xor(v1, 1);
        v0 += __shfl_xor(v0, 2); v1 += __shfl_xor(v1, 2);
        v0 += __shfl_xor(v0, 4); v1 += __shfl_xor(v1, 4);
        v0 += __shfl_xor(v0, 8); v1 += __shfl_xor(v1, 8);
        acc0[e] = v0; acc1[e] = v1;
    }

    // Per-lane slot for block reduction: kind = f>>3 (0=dispatch,1=probs), e = f&7
    const int se = f & 7;
    const int sk = f >> 3;
    float slotv = 0.f;

#pragma unroll
    for (int j = 0; j < 2; ++j) {
        const float* L = j ? acc1 : acc0;
        float mx = L[0];
#pragma unroll
        for (int e = 1; e < E; ++e) mx = fmaxf(mx, L[e]);
        float p[E], s = 0.f;
#pragma unroll
        for (int e = 0; e < E; ++e) { p[e] = expf(L[e] - mx); s += p[e]; }
        const float inv = 1.f / s;
#pragma unroll
        for (int e = 0; e < E; ++e) p[e] *= inv;

        // top-2, strict >, lowest index on ties (lax.top_k semantics)
        int i1 = 0;
#pragma unroll
        for (int e = 1; e < E; ++e) if (p[e] > p[i1]) i1 = e;
        int i2 = -1;
#pragma unroll
        for (int e = 0; e < E; ++e) {
            if (e == i1) continue;
            if (i2 < 0 || p[e] > p[i2]) i2 = e;
        }
        const float s12 = p[i1] + p[i2];
        const float w1 = p[i1] / s12;
        const float w2 = p[i2] / s12;

        const size_t tok = tok0 + j;
        if (f < 8) {
            const float de = (f == i1) ? w1 : ((f == i2) ? w2 : 0.f);
            dispatch[tok * E + f] = de;
        } else {
            probs_out[tok * E + (f - 8)] = p[f - 8];
        }
        slotv += sk ? p[se] : ((se == i1) ? w1 : ((se == i2) ? w2 : 0.f));
    }

    // Block reduction of the 16 slots (reuse w_lds; all waves done with it)
    __syncthreads();
    float* red = w_lds;                  // need 256 floats
    red[wave * 64 + lane] = slotv;       // = red[(wave*4+t)*16 + f]
    __syncthreads();
    if (tid < 16) {
        float s = 0.f;
#pragma unroll
        for (int k = 0; k < 16; ++k) s += red[k * 16 + tid];
        partial[blockIdx.x * 16 + tid] = s;
    }
}

// ---------------------------------------------------------------------------
// Kernel 2: reduce partials -> lb_loss; per-expert capacity enforcement
// (exact radix select, index-ordered ties). Early-exits when under capacity.
// ---------------------------------------------------------------------------
__global__ __launch_bounds__(FBLK) void finalize_kernel(
    float* __restrict__ dispatch,
    const float* __restrict__ partial,
    int nb,
    float* __restrict__ lb_out,
    int N)
{
    const int e    = blockIdx.x;
    const int tid  = threadIdx.x;
    const int lane = tid & 63;
    const int wv   = tid >> 6;           // 16 waves

    __shared__ float g[16];
    {
        float v = 0.f;
        for (int b = lane; b < nb; b += 64) v += partial[(size_t)b * 16 + wv];
#pragma unroll
        for (int off = 32; off; off >>= 1) v += __shfl_xor(v, off);
        if (lane == 0) g[wv] = v;
    }
    __syncthreads();

    if (e == 0 && tid == 0) {
        float s = 0.f;
        for (int i = 0; i < E; ++i) s += g[i] * g[E + i];
        *lb_out = 0.01f * s / (float)N;
    }

    const float tpe = g[e];
    if (!(tpe > (float)CAP)) return;     // block-uniform

    __shared__ unsigned hist[256];
    __shared__ unsigned sh_prefix;
    __shared__ int sh_k;

    unsigned prefix = 0;
    int k = CAP;

    for (int round = 0; round < 4; ++round) {
        const int shift = 24 - 8 * round;
        for (int i = tid; i < 256; i += FBLK) hist[i] = 0;
        __syncthreads();
        const unsigned mhi = (round == 0) ? 0u : (0xFFFFFFFFu << (shift + 8));
        for (int i = tid; i < N; i += FBLK) {
            const unsigned bits = __float_as_uint(dispatch[(size_t)i * E + e]);
            if ((bits & mhi) == (prefix & mhi))
                atomicAdd(&hist[(bits >> shift) & 255u], 1u);
        }
        __syncthreads();
        if (tid == 0) {
            int cum = 0;
            int d = 255;
            for (; d > 0; --d) {
                const int h = (int)hist[d];
                if (cum + h >= k) break;
                cum += h;
            }
            sh_prefix = prefix | ((unsigned)d << shift);
            sh_k = k - cum;
        }
        __syncthreads();
        prefix = sh_prefix;
        k = sh_k;
        __syncthreads();
    }

    const unsigned T = prefix;
    const unsigned r = (unsigned)k;

    __shared__ unsigned wave_cnt[FBLK / 64];
    __shared__ unsigned running;
    if (tid == 0) running = 0;
    __syncthreads();

    for (int base = 0; base < N; base += FBLK) {
        const int i = base + tid;
        const unsigned bits = __float_as_uint(dispatch[(size_t)i * E + e]);
        const bool eq = (bits == T);
        const unsigned long long bal = __ballot(eq);
        if (lane == 0) wave_cnt[wv] = (unsigned)__popcll(bal);
        __syncthreads();
        unsigned before = running;
        for (int w = 0; w < wv; ++w) before += wave_cnt[w];
        const unsigned rank = before + (unsigned)__popcll(bal & ((1ull << lane) - 1ull));
        const bool keep = (bits > T) || (eq && rank < r);
        if (!keep) dispatch[(size_t)i * E + e] = 0.f;
        __syncthreads();
        if (tid == 0) {
            unsigned tot = 0;
            for (int w = 0; w < FBLK / 64; ++w) tot += wave_cnt[w];
            running += tot;
        }
        __syncthreads();
    }
}

// ---------------------------------------------------------------------------
extern "C" void kernel_launch(void* const* d_in, const int* in_sizes, int n_in,
                              void* d_out, int out_size, void* d_ws, size_t ws_size,
                              hipStream_t stream)
{
    const float* hs = (const float*)d_in[0];
    const float* rw = (const float*)d_in[1];
    const int n_tokens = in_sizes[0] / H;          // 32768 (divisible by 32)

    float* dispatch = (float*)d_out;               // [N*E]
    float* lb       = dispatch + (size_t)n_tokens * E;
    float* probs    = lb + 1;                      // [N*E]
    float* partial  = (float*)d_ws;                // [nb*16] fp32, fully written

    const int nb = n_tokens / 32;                  // 8 tokens/wave * 4 waves
    router_kernel<<<nb, BLK, 0, stream>>>(hs, rw, dispatch, probs, partial);
    finalize_kernel<<<E, FBLK, 0, stream>>>(dispatch, partial, nb, lb, n_tokens);
}

// Round 3
// 214.482 us; speedup vs baseline: 1.4992x; 1.0089x over previous
//
#include <hip/hip_runtime.h>

#define H 1024
#define E 8
#define BLK 256
#define CAP 5120       // int(1.25 * 4096 * 8 / 8)
#define FBLK 1024

// ---------------------------------------------------------------------------
// Kernel 1: router logits + softmax + top-2 renorm + outputs + per-block
// partial sums. Wave layout: lane = (t<<4)|f ; t = token-slot (4), f = H-slice
// (16 lanes x float4). Each lane handles 2 tokens: 8 tokens/wave, 32/block.
// __launch_bounds__(256,4): cap VGPRs at 128 so 4 blocks (16 waves) fit per CU
// alongside the 32 KB LDS w-tile. Software-pipelined c-loop keeps live w-regs
// at 16 (two e-groups of 4) instead of letting unroll hoist all 32 ds_reads.
// ---------------------------------------------------------------------------
__global__ __launch_bounds__(BLK, 4) void router_kernel(
    const float* __restrict__ hs,
    const float* __restrict__ rw,
    float* __restrict__ dispatch,
    float* __restrict__ probs_out,
    float* __restrict__ partial)   // [16][nb] slot-major
{
    __shared__ float w_lds[E * H];   // 32 KB, read-only after first barrier

    const int tid = threadIdx.x;
    for (int i = tid; i < E * H / 4; i += BLK)
        ((float4*)w_lds)[i] = ((const float4*)rw)[i];
    __syncthreads();

    const int wave = tid >> 6;
    const int lane = tid & 63;
    const int t    = lane >> 4;     // token slot within wave
    const int f    = lane & 15;     // H-slice: floats c*64 + 4f..4f+3
    const int wid  = blockIdx.x * (BLK / 64) + wave;
    const size_t tok0 = (size_t)wid * 8 + t * 2;

    float acc0[E], acc1[E];
#pragma unroll
    for (int e = 0; e < E; ++e) { acc0[e] = 0.f; acc1[e] = 0.f; }

    const float* h0 = hs + tok0 * H + 4 * f;

    // software pipeline: global loads for c+1 issued before FMAs of c
    float4 a0 = *(const float4*)(h0);
    float4 a1 = *(const float4*)(h0 + H);
#pragma unroll 2
    for (int c = 0; c < 16; ++c) {
        float4 n0 = a0, n1 = a1;
        if (c < 15) {
            n0 = *(const float4*)(h0 + (c + 1) * 64);
            n1 = *(const float4*)(h0 + H + (c + 1) * 64);
        }
        const float* wb = w_lds + c * 64 + 4 * f;
#pragma unroll
        for (int eg = 0; eg < 2; ++eg) {
            float4 wv[4];
#pragma unroll
            for (int q = 0; q < 4; ++q)
                wv[q] = *(const float4*)(wb + (eg * 4 + q) * H);  // broadcast/2-way: free
#pragma unroll
            for (int q = 0; q < 4; ++q) {
                const int e = eg * 4 + q;
                acc0[e] = fmaf(a0.x, wv[q].x, acc0[e]);
                acc0[e] = fmaf(a0.y, wv[q].y, acc0[e]);
                acc0[e] = fmaf(a0.z, wv[q].z, acc0[e]);
                acc0[e] = fmaf(a0.w, wv[q].w, acc0[e]);
                acc1[e] = fmaf(a1.x, wv[q].x, acc1[e]);
                acc1[e] = fmaf(a1.y, wv[q].y, acc1[e]);
                acc1[e] = fmaf(a1.z, wv[q].z, acc1[e]);
                acc1[e] = fmaf(a1.w, wv[q].w, acc1[e]);
            }
        }
        a0 = n0; a1 = n1;
    }

    // Reduce partial dots across the 16 f-lanes (butterfly)
#pragma unroll
    for (int e = 0; e < E; ++e) {
        float v0 = acc0[e], v1 = acc1[e];
        v0 += __shfl_xor(v0, 1); v1 += __shfl_xor(v1, 1);
        v0 += __shfl_xor(v0, 2); v1 += __shfl_xor(v1, 2);
        v0 += __shfl_xor(v0, 4); v1 += __shfl_xor(v1, 4);
        v0 += __shfl_xor(v0, 8); v1 += __shfl_xor(v1, 8);
        acc0[e] = v0; acc1[e] = v1;
    }

    // Per-lane slot for block reduction: slot = f (0..7 dispatch, 8..15 probs)
    const int se = f & 7;
    const int sk = f >> 3;
    float slotv = 0.f;

#pragma unroll
    for (int j = 0; j < 2; ++j) {
        const float* L = j ? acc1 : acc0;
        float mx = L[0];
#pragma unroll
        for (int e = 1; e < E; ++e) mx = fmaxf(mx, L[e]);
        float p[E], s = 0.f;
#pragma unroll
        for (int e = 0; e < E; ++e) { p[e] = expf(L[e] - mx); s += p[e]; }
        const float inv = 1.f / s;
#pragma unroll
        for (int e = 0; e < E; ++e) p[e] *= inv;

        // top-2, strict >, lowest index on ties (lax.top_k semantics)
        int i1 = 0;
#pragma unroll
        for (int e = 1; e < E; ++e) if (p[e] > p[i1]) i1 = e;
        int i2 = -1;
#pragma unroll
        for (int e = 0; e < E; ++e) {
            if (e == i1) continue;
            if (i2 < 0 || p[e] > p[i2]) i2 = e;
        }
        const float s12 = p[i1] + p[i2];
        const float w1 = p[i1] / s12;
        const float w2 = p[i2] / s12;

        const size_t tok = tok0 + j;
        if (f < 8) {
            const float de = (f == i1) ? w1 : ((f == i2) ? w2 : 0.f);
            dispatch[tok * E + f] = de;
        } else {
            probs_out[tok * E + (f - 8)] = p[f - 8];
        }
        slotv += sk ? p[se] : ((se == i1) ? w1 : ((se == i2) ? w2 : 0.f));
    }

    // Block reduction of the 16 slots (reuse w_lds; all waves done with it)
    __syncthreads();
    float* red = w_lds;                  // 256 floats
    red[wave * 64 + lane] = slotv;
    __syncthreads();
    if (tid < 16) {
        float s = 0.f;
#pragma unroll
        for (int k = 0; k < 16; ++k) s += red[k * 16 + tid];
        partial[(size_t)tid * gridDim.x + blockIdx.x] = s;   // slot-major
    }
}

// ---------------------------------------------------------------------------
// Kernel 2: reduce partials -> lb_loss; per-expert capacity enforcement
// (exact radix select, index-ordered ties). Early-exits when under capacity.
// ---------------------------------------------------------------------------
__global__ __launch_bounds__(FBLK) void finalize_kernel(
    float* __restrict__ dispatch,
    const float* __restrict__ partial,
    int nb,
    float* __restrict__ lb_out,
    int N)
{
    const int e    = blockIdx.x;
    const int tid  = threadIdx.x;
    const int lane = tid & 63;
    const int wv   = tid >> 6;           // 16 waves -> 16 slots

    __shared__ float g[16];
    {
        float v = 0.f;
        for (int b = lane; b < nb; b += 64) v += partial[(size_t)wv * nb + b];
#pragma unroll
        for (int off = 32; off; off >>= 1) v += __shfl_xor(v, off);
        if (lane == 0) g[wv] = v;
    }
    __syncthreads();

    if (e == 0 && tid == 0) {
        float s = 0.f;
        for (int i = 0; i < E; ++i) s += g[i] * g[E + i];
        *lb_out = 0.01f * s / (float)N;
    }

    const float tpe = g[e];
    if (!(tpe > (float)CAP)) return;     // block-uniform

    __shared__ unsigned hist[256];
    __shared__ unsigned sh_prefix;
    __shared__ int sh_k;

    unsigned prefix = 0;
    int k = CAP;

    for (int round = 0; round < 4; ++round) {
        const int shift = 24 - 8 * round;
        for (int i = tid; i < 256; i += FBLK) hist[i] = 0;
        __syncthreads();
        const unsigned mhi = (round == 0) ? 0u : (0xFFFFFFFFu << (shift + 8));
        for (int i = tid; i < N; i += FBLK) {
            const unsigned bits = __float_as_uint(dispatch[(size_t)i * E + e]);
            if ((bits & mhi) == (prefix & mhi))
                atomicAdd(&hist[(bits >> shift) & 255u], 1u);
        }
        __syncthreads();
        if (tid == 0) {
            int cum = 0;
            int d = 255;
            for (; d > 0; --d) {
                const int h = (int)hist[d];
                if (cum + h >= k) break;
                cum += h;
            }
            sh_prefix = prefix | ((unsigned)d << shift);
            sh_k = k - cum;
        }
        __syncthreads();
        prefix = sh_prefix;
        k = sh_k;
        __syncthreads();
    }

    const unsigned T = prefix;
    const unsigned r = (unsigned)k;

    __shared__ unsigned wave_cnt[FBLK / 64];
    __shared__ unsigned running;
    if (tid == 0) running = 0;
    __syncthreads();

    for (int base = 0; base < N; base += FBLK) {
        const int i = base + tid;
        const unsigned bits = __float_as_uint(dispatch[(size_t)i * E + e]);
        const bool eq = (bits == T);
        const unsigned long long bal = __ballot(eq);
        if (lane == 0) wave_cnt[wv] = (unsigned)__popcll(bal);
        __syncthreads();
        unsigned before = running;
        for (int w = 0; w < wv; ++w) before += wave_cnt[w];
        const unsigned rank = before + (unsigned)__popcll(bal & ((1ull << lane) - 1ull));
        const bool keep = (bits > T) || (eq && rank < r);
        if (!keep) dispatch[(size_t)i * E + e] = 0.f;
        __syncthreads();
        if (tid == 0) {
            unsigned tot = 0;
            for (int w = 0; w < FBLK / 64; ++w) tot += wave_cnt[w];
            running += tot;
        }
        __syncthreads();
    }
}

// ---------------------------------------------------------------------------
extern "C" void kernel_launch(void* const* d_in, const int* in_sizes, int n_in,
                              void* d_out, int out_size, void* d_ws, size_t ws_size,
                              hipStream_t stream)
{
    const float* hs = (const float*)d_in[0];
    const float* rw = (const float*)d_in[1];
    const int n_tokens = in_sizes[0] / H;          // 32768

    float* dispatch = (float*)d_out;               // [N*E]
    float* lb       = dispatch + (size_t)n_tokens * E;
    float* probs    = lb + 1;                      // [N*E]
    float* partial  = (float*)d_ws;                // [16][nb] fp32, fully written

    const int nb = n_tokens / 32;                  // 32 tokens/block -> 1024
    router_kernel<<<nb, BLK, 0, stream>>>(hs, rw, dispatch, probs, partial);
    finalize_kernel<<<E, FBLK, 0, stream>>>(dispatch, partial, nb, lb, n_tokens);
}

// Round 4
// 207.476 us; speedup vs baseline: 1.5498x; 1.0338x over previous
//
#include <hip/hip_runtime.h>

#define H 1024
#define E 8
#define BLK 256
#define CAP 5120       // int(1.25 * 4096 * 8 / 8)
#define FBLK 1024

typedef float f32x4 __attribute__((ext_vector_type(4)));

// ---------------------------------------------------------------------------
// Kernel 1: pure streaming GEMV — logits[N][8] = hs[N][1024] . rw[8][1024]^T
// Wave layout: lane = (t<<4)|f ; t = token-slot (4), f = H-slice (16 x float4).
// 2 tokens/lane, 8 tokens/wave, 32/block, grid = N/32 = 1024 blocks.
// Nontemporal h loads (no reuse) + explicit depth-2 prefetch (4 loads in
// flight/wave). w in 32 KB LDS (broadcast/2-way reads = conflict-free).
// ---------------------------------------------------------------------------
__global__ __launch_bounds__(BLK, 4) void logits_kernel(
    const float* __restrict__ hs,
    const float* __restrict__ rw,
    float* __restrict__ logits)
{
    __shared__ float w_lds[E * H];   // 32 KB

    const int tid = threadIdx.x;
    for (int i = tid; i < E * H / 4; i += BLK)
        ((f32x4*)w_lds)[i] = ((const f32x4*)rw)[i];

    const int wave = tid >> 6;
    const int lane = tid & 63;
    const int t    = lane >> 4;
    const int f    = lane & 15;
    const int wid  = blockIdx.x * (BLK / 64) + wave;
    const size_t tok0 = (size_t)wid * 8 + t * 2;
    const float* h0 = hs + tok0 * H + 4 * f;

    // depth-2 prefetch: issue before the barrier so they overlap the w-stage
    f32x4 A0[2], A1[2];
    A0[0] = __builtin_nontemporal_load((const f32x4*)(h0));
    A1[0] = __builtin_nontemporal_load((const f32x4*)(h0 + H));
    A0[1] = __builtin_nontemporal_load((const f32x4*)(h0 + 64));
    A1[1] = __builtin_nontemporal_load((const f32x4*)(h0 + H + 64));

    __syncthreads();

    float acc0[E], acc1[E];
#pragma unroll
    for (int e = 0; e < E; ++e) { acc0[e] = 0.f; acc1[e] = 0.f; }

#pragma unroll 2
    for (int c = 0; c < 16; ++c) {
        const int cur = c & 1;
        const f32x4 a0 = A0[cur], a1 = A1[cur];
        if (c < 14) {
            A0[cur] = __builtin_nontemporal_load((const f32x4*)(h0 + (c + 2) * 64));
            A1[cur] = __builtin_nontemporal_load((const f32x4*)(h0 + H + (c + 2) * 64));
        }
        const float* wb = w_lds + c * 64 + 4 * f;
#pragma unroll
        for (int eg = 0; eg < 2; ++eg) {
            f32x4 wv[4];
#pragma unroll
            for (int q = 0; q < 4; ++q)
                wv[q] = *(const f32x4*)(wb + (eg * 4 + q) * H);
#pragma unroll
            for (int q = 0; q < 4; ++q) {
                const int e = eg * 4 + q;
                acc0[e] = fmaf(a0[0], wv[q][0], acc0[e]);
                acc0[e] = fmaf(a0[1], wv[q][1], acc0[e]);
                acc0[e] = fmaf(a0[2], wv[q][2], acc0[e]);
                acc0[e] = fmaf(a0[3], wv[q][3], acc0[e]);
                acc1[e] = fmaf(a1[0], wv[q][0], acc1[e]);
                acc1[e] = fmaf(a1[1], wv[q][1], acc1[e]);
                acc1[e] = fmaf(a1[2], wv[q][2], acc1[e]);
                acc1[e] = fmaf(a1[3], wv[q][3], acc1[e]);
            }
        }
    }

    // Butterfly over the 16 f-lanes (same order as prior rounds)
#pragma unroll
    for (int e = 0; e < E; ++e) {
        float v0 = acc0[e], v1 = acc1[e];
        v0 += __shfl_xor(v0, 1); v1 += __shfl_xor(v1, 1);
        v0 += __shfl_xor(v0, 2); v1 += __shfl_xor(v1, 2);
        v0 += __shfl_xor(v0, 4); v1 += __shfl_xor(v1, 4);
        v0 += __shfl_xor(v0, 8); v1 += __shfl_xor(v1, 8);
        acc0[e] = v0; acc1[e] = v1;
    }

    // Combined store: f<8 -> token tok0 row, f>=8 -> token tok0+1 row.
    // (tok0+1)*8 + (f-8) == tok0*8 + f : one contiguous 64B run per t-group.
    const float outv = (f < 8) ? acc0[f] : acc1[f - 8];
    logits[tok0 * 8 + f] = outv;
}

// ---------------------------------------------------------------------------
// Kernel 2: thread-per-token softmax + top-2 renorm + outputs + partials.
// 256 tokens/block, grid = N/256 = 128 blocks. All row I/O is 16B-vectorized.
// ---------------------------------------------------------------------------
__global__ __launch_bounds__(256) void softmax_kernel(
    const float* __restrict__ logits,
    float* __restrict__ dispatch,
    float* __restrict__ probs_out,
    float* __restrict__ partial,   // [16][nb2] slot-major
    int nb2)
{
    __shared__ float red[4][16];
    const int tid  = threadIdx.x;
    const int lane = tid & 63;
    const int wv   = tid >> 6;
    const size_t tok = (size_t)blockIdx.x * 256 + tid;

    const f32x4 l0 = *(const f32x4*)(logits + tok * 8);
    const f32x4 l1 = *(const f32x4*)(logits + tok * 8 + 4);
    float L[E] = {l0[0], l0[1], l0[2], l0[3], l1[0], l1[1], l1[2], l1[3]};

    float mx = L[0];
#pragma unroll
    for (int e = 1; e < E; ++e) mx = fmaxf(mx, L[e]);
    float p[E], s = 0.f;
#pragma unroll
    for (int e = 0; e < E; ++e) { p[e] = expf(L[e] - mx); s += p[e]; }
    const float inv = 1.f / s;
#pragma unroll
    for (int e = 0; e < E; ++e) p[e] *= inv;

    // top-2, strict >, lowest index on ties (lax.top_k semantics)
    int i1 = 0;
#pragma unroll
    for (int e = 1; e < E; ++e) if (p[e] > p[i1]) i1 = e;
    int i2 = -1;
#pragma unroll
    for (int e = 0; e < E; ++e) {
        if (e == i1) continue;
        if (i2 < 0 || p[e] > p[i2]) i2 = e;
    }
    const float s12 = p[i1] + p[i2];
    const float w1 = p[i1] / s12;
    const float w2 = p[i2] / s12;

    float d[E];
#pragma unroll
    for (int e = 0; e < E; ++e) d[e] = (e == i1) ? w1 : ((e == i2) ? w2 : 0.f);

    f32x4 v;
    v[0] = d[0]; v[1] = d[1]; v[2] = d[2]; v[3] = d[3];
    *(f32x4*)(dispatch + tok * 8) = v;
    v[0] = d[4]; v[1] = d[5]; v[2] = d[6]; v[3] = d[7];
    *(f32x4*)(dispatch + tok * 8 + 4) = v;
    v[0] = p[0]; v[1] = p[1]; v[2] = p[2]; v[3] = p[3];
    *(f32x4*)(probs_out + tok * 8) = v;
    v[0] = p[4]; v[1] = p[5]; v[2] = p[6]; v[3] = p[7];
    *(f32x4*)(probs_out + tok * 8 + 4) = v;

    // per-block partials: slots 0..7 = dispatch sums, 8..15 = prob sums
#pragma unroll
    for (int e = 0; e < E; ++e) {
        float v1 = d[e], v2 = p[e];
#pragma unroll
        for (int off = 32; off; off >>= 1) {
            v1 += __shfl_xor(v1, off);
            v2 += __shfl_xor(v2, off);
        }
        if (lane == 0) { red[wv][e] = v1; red[wv][E + e] = v2; }
    }
    __syncthreads();
    if (tid < 16) {
        const float s2 = red[0][tid] + red[1][tid] + red[2][tid] + red[3][tid];
        partial[(size_t)tid * nb2 + blockIdx.x] = s2;
    }
}

// ---------------------------------------------------------------------------
// Kernel 3: reduce partials -> lb_loss; per-expert capacity enforcement
// (exact radix select, index-ordered ties). Early-exits when under capacity.
// ---------------------------------------------------------------------------
__global__ __launch_bounds__(FBLK) void finalize_kernel(
    float* __restrict__ dispatch,
    const float* __restrict__ partial,
    int nb,
    float* __restrict__ lb_out,
    int N)
{
    const int e    = blockIdx.x;
    const int tid  = threadIdx.x;
    const int lane = tid & 63;
    const int wv   = tid >> 6;           // 16 waves -> 16 slots

    __shared__ float g[16];
    {
        float v = 0.f;
        for (int b = lane; b < nb; b += 64) v += partial[(size_t)wv * nb + b];
#pragma unroll
        for (int off = 32; off; off >>= 1) v += __shfl_xor(v, off);
        if (lane == 0) g[wv] = v;
    }
    __syncthreads();

    if (e == 0 && tid == 0) {
        float s = 0.f;
        for (int i = 0; i < E; ++i) s += g[i] * g[E + i];
        *lb_out = 0.01f * s / (float)N;
    }

    const float tpe = g[e];
    if (!(tpe > (float)CAP)) return;     // block-uniform

    __shared__ unsigned hist[256];
    __shared__ unsigned sh_prefix;
    __shared__ int sh_k;

    unsigned prefix = 0;
    int k = CAP;

    for (int round = 0; round < 4; ++round) {
        const int shift = 24 - 8 * round;
        for (int i = tid; i < 256; i += FBLK) hist[i] = 0;
        __syncthreads();
        const unsigned mhi = (round == 0) ? 0u : (0xFFFFFFFFu << (shift + 8));
        for (int i = tid; i < N; i += FBLK) {
            const unsigned bits = __float_as_uint(dispatch[(size_t)i * E + e]);
            if ((bits & mhi) == (prefix & mhi))
                atomicAdd(&hist[(bits >> shift) & 255u], 1u);
        }
        __syncthreads();
        if (tid == 0) {
            int cum = 0;
            int d = 255;
            for (; d > 0; --d) {
                const int h = (int)hist[d];
                if (cum + h >= k) break;
                cum += h;
            }
            sh_prefix = prefix | ((unsigned)d << shift);
            sh_k = k - cum;
        }
        __syncthreads();
        prefix = sh_prefix;
        k = sh_k;
        __syncthreads();
    }

    const unsigned T = prefix;
    const unsigned r = (unsigned)k;

    __shared__ unsigned wave_cnt[FBLK / 64];
    __shared__ unsigned running;
    if (tid == 0) running = 0;
    __syncthreads();

    for (int base = 0; base < N; base += FBLK) {
        const int i = base + tid;
        const unsigned bits = __float_as_uint(dispatch[(size_t)i * E + e]);
        const bool eq = (bits == T);
        const unsigned long long bal = __ballot(eq);
        if (lane == 0) wave_cnt[wv] = (unsigned)__popcll(bal);
        __syncthreads();
        unsigned before = running;
        for (int w = 0; w < wv; ++w) before += wave_cnt[w];
        const unsigned rank = before + (unsigned)__popcll(bal & ((1ull << lane) - 1ull));
        const bool keep = (bits > T) || (eq && rank < r);
        if (!keep) dispatch[(size_t)i * E + e] = 0.f;
        __syncthreads();
        if (tid == 0) {
            unsigned tot = 0;
            for (int w = 0; w < FBLK / 64; ++w) tot += wave_cnt[w];
            running += tot;
        }
        __syncthreads();
    }
}

// ---------------------------------------------------------------------------
extern "C" void kernel_launch(void* const* d_in, const int* in_sizes, int n_in,
                              void* d_out, int out_size, void* d_ws, size_t ws_size,
                              hipStream_t stream)
{
    const float* hs = (const float*)d_in[0];
    const float* rw = (const float*)d_in[1];
    const int n_tokens = in_sizes[0] / H;          // 32768

    float* dispatch = (float*)d_out;               // [N*E]
    float* lb       = dispatch + (size_t)n_tokens * E;
    float* probs    = lb + 1;                      // [N*E]

    float* logits   = (float*)d_ws;                // [N*E] fp32
    float* partial  = logits + (size_t)n_tokens * E;  // [16][nb2]

    const int nb1 = n_tokens / 32;                 // 1024 blocks
    const int nb2 = n_tokens / 256;                // 128 blocks

    logits_kernel<<<nb1, BLK, 0, stream>>>(hs, rw, logits);
    softmax_kernel<<<nb2, 256, 0, stream>>>(logits, dispatch, probs, partial, nb2);
    finalize_kernel<<<E, FBLK, 0, stream>>>(dispatch, partial, nb2, lb, n_tokens);
}